// Round 6
// baseline (79.492 us; speedup 1.0000x reference)
//
#include <hip/hip_runtime.h>

#define N_IMG 32
#define H_IMG 224
#define W_IMG 224

// block ranges in the fused grid:
// S=1 : [0, 1568)      32*224*56 vec4-threads
// S=2 : [1568, 1960)   32*112*28
// S=4 : [1960, 2058)   32*56*14
// S=8 : [2058, 2083)   32*28*7  (last block partial)
// S=16: [2083, 2108)   32*14*14 scalar (last block partial)
#define NBLK_TOTAL 2108
#define B1_END 1568
#define B2_END 1960
#define B4_END 2058
#define B8_END 2083

__device__ __forceinline__ int reflect_idx(int i, int n) {
    if (i < 0) return -i;
    if (i >= n) return 2 * n - 2 - i;
    return i;
}

// bin = floor(atan2(gx,gy)/pi*9) mod 9 without atan2: direction-only sector count.
__device__ __forceinline__ int bin_from_g(float gx, float gy) {
    float u = gx * __builtin_copysignf(1.0f, gy);
    float w = __builtin_fabsf(gy);
    const float T[9] = {-5.6712818f, -1.7320508f, -0.83909963f, -0.36397023f,
                        0.0f, 0.36397023f, 0.83909963f, 1.7320508f, 5.6712818f};
    int c = 0;
    #pragma unroll
    for (int k = 0; k < 9; ++k) c += (u >= T[k] * w) ? 1 : 0;
    int b = c + 4;
    return (b >= 9) ? b - 9 : b;
}

// scalar-path Sobel mag+bin at (y,x)
__device__ __forceinline__ void magbin_at(const float* __restrict__ im,
        int y, int x, float& mag, int& bn)
{
    int y0 = reflect_idx(y - 1, H_IMG), y2 = reflect_idx(y + 1, H_IMG);
    int x0 = reflect_idx(x - 1, W_IMG), x2 = reflect_idx(x + 1, W_IMG);
    const float* q0 = im + (size_t)y0 * W_IMG;
    const float* q1 = im + (size_t)y  * W_IMG;
    const float* q2 = im + (size_t)y2 * W_IMG;
    float p00 = q0[x0], p01 = q0[x], p02 = q0[x2];
    float p10 = q1[x0],              p12 = q1[x2];
    float p20 = q2[x0], p21 = q2[x], p22 = q2[x2];
    float gx = (p00 - p02) + 2.0f * (p10 - p12) + (p20 - p22);
    float gy = (p00 - p20) + 2.0f * (p01 - p21) + (p02 - p22);
    mag = sqrtf(gx * gx + gy * gy);
    bn = bin_from_g(gx, gy);
}

// ======================= S == 1 specialized path =======================

struct Rows { float r0[6], r1[6], r2[6]; };

// issue the 9 loads (3 rows x {edge scalar, aligned float4, edge scalar}) for one channel
template<int CC>
__device__ __forceinline__ Rows load_rows(const float* __restrict__ imgs,
    int n, int i, int j0, int y0, int y2, int xl, int xr)
{
    const float* im = imgs + (size_t)(n * 3 + CC) * H_IMG * W_IMG;
    const float* q0 = im + (size_t)y0 * W_IMG;
    const float* q1 = im + (size_t)i  * W_IMG;
    const float* q2 = im + (size_t)y2 * W_IMG;
    Rows R;
    float4 f;
    R.r0[0] = q0[xl]; f = *(const float4*)(q0 + j0);
    R.r0[1] = f.x; R.r0[2] = f.y; R.r0[3] = f.z; R.r0[4] = f.w; R.r0[5] = q0[xr];
    R.r1[0] = q1[xl]; f = *(const float4*)(q1 + j0);
    R.r1[1] = f.x; R.r1[2] = f.y; R.r1[3] = f.z; R.r1[4] = f.w; R.r1[5] = q1[xr];
    R.r2[0] = q2[xl]; f = *(const float4*)(q2 + j0);
    R.r2[1] = f.x; R.r2[2] = f.y; R.r2[3] = f.z; R.r2[4] = f.w; R.r2[5] = q2[xr];
    return R;
}

template<int CC>
__device__ __forceinline__ void stage_pred9_s1(const float* __restrict__ pred,
    int n, int i, int j0, float4 (&buf)[9])
{
    constexpr size_t cstride = (size_t)H_IMG * W_IMG;
    const float* prc = pred + ((size_t)(n * 27 + CC * 9) * H_IMG + i) * W_IMG + j0;
    #pragma unroll
    for (int o = 0; o < 9; ++o) buf[o] = *(const float4*)(prc + o * cstride);
}

// consume one channel's rows -> mag/bin/inv (frees the row registers)
__device__ __forceinline__ void sobel_rows(const Rows& R,
    const float* sA, const float* sB, float Cc,
    float (&mag)[4], int (&bn)[4], float (&inv)[4])
{
    #pragma unroll
    for (int v = 0; v < 4; ++v) {
        float gx = (R.r0[v] - R.r0[v + 2]) + 2.0f * (R.r1[v] - R.r1[v + 2]) + (R.r2[v] - R.r2[v + 2]);
        float gy = (R.r0[v] - R.r2[v]) + 2.0f * (R.r0[v + 1] - R.r2[v + 1]) + (R.r0[v + 2] - R.r2[v + 2]);
        float m = sqrtf(gx * gx + gy * gy);
        int b = bin_from_g(gx, gy);
        mag[v] = m;
        bn[v] = b;
        float nrm2 = fmaf(m, fmaf(m, sA[b], 2.0f * sB[b]), Cc);
        inv[v] = 1.0f / fmaxf(sqrtf(nrm2), 1e-12f);
    }
}

__device__ __forceinline__ void consume9(const float4 (&buf)[9],
    const float* spwT, const float* spb,
    const float (&mag)[4], const int (&bn)[4], const float (&inv)[4],
    float (&d2)[4])
{
    #pragma unroll
    for (int o = 0; o < 9; ++o) {
        float pbo = spb[o];
        float pe[4] = {buf[o].x, buf[o].y, buf[o].z, buf[o].w};
        #pragma unroll
        for (int u = 0; u < 4; ++u) {
            float h = fmaf(spwT[bn[u] * 9 + o], mag[u], pbo) * inv[u];
            float dd = pe[u] - h;
            d2[u] += dd * dd;
        }
    }
}

__device__ __forceinline__ void s1_body(int rel_bid,
    const float* __restrict__ imgs, const float* __restrict__ mask,
    const float* __restrict__ pred,
    const float* spwT, const float* spb, const float* sA, const float* sB,
    float Cc, float& local, float& mlocal)
{
    constexpr int WsV = W_IMG / 4;
    int vt = rel_bid * 256 + (int)threadIdx.x;
    int jv = vt % WsV;
    int t  = vt / WsV;
    int i  = t % H_IMG;
    int n  = t / H_IMG;
    int j0 = jv * 4;

    int y0 = reflect_idx(i - 1, H_IMG), y2 = reflect_idx(i + 1, H_IMG);
    int xl = reflect_idx(j0 - 1, W_IMG), xr = reflect_idx(j0 + 4, W_IMG);

    // ---------- issue phase (issue order == consume order) ----------
    // mask first (consumed last; by then everything is drained anyway)
    float4 mv = *(const float4*)(mask + (size_t)n * H_IMG * W_IMG + (size_t)i * W_IMG + j0);

    Rows RA = load_rows<0>(imgs, n, i, j0, y0, y2, xl, xr);   // 9 loads
    Rows RB = load_rows<1>(imgs, n, i, j0, y0, y2, xl, xr);   // 9 loads
    Rows RC = load_rows<2>(imgs, n, i, j0, y0, y2, xl, xr);   // 9 loads
    float4 pq0[9], pq1[9];
    stage_pred9_s1<0>(pred, n, i, j0, pq0);                    // 9 loads

    // ---------- consume phase ----------
    // sobel A waits only on the OLDEST loads; RB/RC/pq0 stay in flight
    float magA[4], invA[4]; int bnA[4];
    sobel_rows(RA, sA, sB, Cc, magA, bnA, invA);
    float magB[4], invB[4]; int bnB[4];
    sobel_rows(RB, sA, sB, Cc, magB, bnB, invB);
    float magC[4], invC[4]; int bnC[4];
    sobel_rows(RC, sA, sB, Cc, magC, bnC, invC);

    float d2[4] = {0.0f, 0.0f, 0.0f, 0.0f};
    stage_pred9_s1<1>(pred, n, i, j0, pq1);     // c=1 flies while consuming c=0
    consume9(pq0, spwT, spb, magA, bnA, invA, d2);
    stage_pred9_s1<2>(pred, n, i, j0, pq0);     // c=2 flies while consuming c=1
    consume9(pq1, spwT, spb, magB, bnB, invB, d2);
    consume9(pq0, spwT, spb, magC, bnC, invC, d2);

    float Mv[4] = {mv.x, mv.y, mv.z, mv.w};
    float acc = 0.0f, macc = 0.0f;
    #pragma unroll
    for (int v = 0; v < 4; ++v) { acc += Mv[v] * d2[v]; macc += Mv[v]; }
    local = acc * (1.0f / 27.0f);
    mlocal = macc;   // sum of M at s=1 == sum(mask)
}

// ======================= generic S >= 2 path =======================

template <int S, int VEC>
__device__ __forceinline__ void scale_body(int rel_bid,
    const float* __restrict__ imgs, const float* __restrict__ mask,
    const float* __restrict__ pred,
    const float* spwT, const float* spb, const float* sA, const float* sB,
    float Cc, float& local, float& mlocal)
{
    constexpr int Hs = H_IMG / S, Ws = W_IMG / S;
    constexpr int WsV = Ws / VEC;
    int vt = rel_bid * 256 + (int)threadIdx.x;
    if (vt >= N_IMG * Hs * WsV) return;
    int jv = vt % WsV;
    int t  = vt / WsV;
    int i  = t % Hs;
    int n  = t / Hs;
    int j0 = jv * VEC;

    // ---- mask pooling (unroll-limited: keep this branch's VGPR cost low) ----
    float msum[VEC];
    #pragma unroll
    for (int v = 0; v < VEC; ++v) msum[v] = 0.0f;
    const float* mbase = mask + (size_t)n * H_IMG * W_IMG;
    #pragma unroll 2
    for (int a = 0; a < S; ++a) {
        const float* mr = mbase + (size_t)(i * S + a) * W_IMG + j0 * S;
        #pragma unroll
        for (int q = 0; q < (S * VEC) / 4; ++q) {
            float4 fv = *(const float4*)(mr + q * 4);
            float me[4] = {fv.x, fv.y, fv.z, fv.w};
            #pragma unroll
            for (int u = 0; u < 4; ++u) msum[(q * 4 + u) / S] += me[u];
        }
    }

    float d2[VEC];
    #pragma unroll
    for (int v = 0; v < VEC; ++v) d2[v] = 0.0f;
    constexpr size_t cstride = (size_t)Hs * Ws;

    #pragma unroll
    for (int c = 0; c < 3; ++c) {
        const float* im = imgs + (size_t)(n * 3 + c) * H_IMG * W_IMG;
        const float* pr = pred + ((size_t)(n * 27 + c * 9) * Hs + i) * Ws + j0;

        float mag[VEC], inv[VEC];
        int bn[VEC];
        #pragma unroll
        for (int v = 0; v < VEC; ++v)
            magbin_at(im, i * S, (j0 + v) * S, mag[v], bn[v]);
        #pragma unroll
        for (int v = 0; v < VEC; ++v) {
            float nrm2 = fmaf(mag[v], fmaf(mag[v], sA[bn[v]], 2.0f * sB[bn[v]]), Cc);
            inv[v] = 1.0f / fmaxf(sqrtf(nrm2), 1e-12f);
        }
        #pragma unroll
        for (int o = 0; o < 9; ++o) {
            float pbo = spb[o];
            if constexpr (VEC == 4) {
                float4 p = *(const float4*)(pr + o * cstride);
                float pe[4] = {p.x, p.y, p.z, p.w};
                #pragma unroll
                for (int u = 0; u < 4; ++u) {
                    float h = fmaf(spwT[bn[u] * 9 + o], mag[u], pbo) * inv[u];
                    float dd = pe[u] - h;
                    d2[u] += dd * dd;
                }
            } else {
                float h = fmaf(spwT[bn[0] * 9 + o], mag[0], pbo) * inv[0];
                float dd = pr[o * cstride] - h;
                d2[0] += dd * dd;
            }
        }
    }

    float acc = 0.0f, macc = 0.0f;
    #pragma unroll
    for (int v = 0; v < VEC; ++v) {
        float M = msum[v] * (1.0f / (float)(S * S));
        acc += M * d2[v];
        macc += M;
    }
    local = acc * (1.0f / 27.0f);
    (void)mlocal;
}

__global__ void __launch_bounds__(256) fused_kernel(
    const float* __restrict__ imgs, const float* __restrict__ mask,
    const float* __restrict__ pred0, const float* __restrict__ pred1,
    const float* __restrict__ pred2, const float* __restrict__ pred3,
    const float* __restrict__ pred4,
    const float* __restrict__ pw0, const float* __restrict__ pw1,
    const float* __restrict__ pw2, const float* __restrict__ pw3,
    const float* __restrict__ pw4,
    const float* __restrict__ pb0, const float* __restrict__ pb1,
    const float* __restrict__ pb2, const float* __restrict__ pb3,
    const float* __restrict__ pb4,
    double* __restrict__ pl, double* __restrict__ pm)
{
    __shared__ float spwT[81];   // spwT[b*9+o] = pw[o*9+b]
    __shared__ float spb[9];
    __shared__ float sA[9], sB[9], sC[1];

    int bid = blockIdx.x;
    // input order: k=0 -> s=16 ... k=4 -> s=1
    const float* pw;  const float* pb;
    if (bid < B1_END)      { pw = pw4; pb = pb4; }
    else if (bid < B2_END) { pw = pw3; pb = pb3; }
    else if (bid < B4_END) { pw = pw2; pb = pb2; }
    else if (bid < B8_END) { pw = pw1; pb = pb1; }
    else                   { pw = pw0; pb = pb0; }

    if (threadIdx.x < 81) {
        int o = threadIdx.x / 9, b = threadIdx.x % 9;
        spwT[b * 9 + o] = pw[threadIdx.x];
    }
    if (threadIdx.x < 9) spb[threadIdx.x] = pb[threadIdx.x];
    __syncthreads();
    if (threadIdx.x < 9) {
        float A = 0.0f, B = 0.0f;
        #pragma unroll
        for (int o = 0; o < 9; ++o) {
            float w = spwT[threadIdx.x * 9 + o];
            A += w * w;
            B += w * spb[o];
        }
        sA[threadIdx.x] = A;
        sB[threadIdx.x] = B;
        if (threadIdx.x == 0) {
            float Cc = 0.0f;
            #pragma unroll
            for (int o = 0; o < 9; ++o) Cc += spb[o] * spb[o];
            sC[0] = Cc;
        }
    }
    __syncthreads();
    float Cc = sC[0];

    float local = 0.0f, mlocal = 0.0f;
    if (bid < B1_END)       s1_body(bid, imgs, mask, pred4, spwT, spb, sA, sB, Cc, local, mlocal);
    else if (bid < B2_END)  scale_body<2, 4>(bid - B1_END,  imgs, mask, pred3, spwT, spb, sA, sB, Cc, local, mlocal);
    else if (bid < B4_END)  scale_body<4, 4>(bid - B2_END,  imgs, mask, pred2, spwT, spb, sA, sB, Cc, local, mlocal);
    else if (bid < B8_END)  scale_body<8, 4>(bid - B4_END,  imgs, mask, pred1, spwT, spb, sA, sB, Cc, local, mlocal);
    else                    scale_body<16, 1>(bid - B8_END, imgs, mask, pred0, spwT, spb, sA, sB, Cc, local, mlocal);

    #pragma unroll
    for (int off = 32; off > 0; off >>= 1) {
        local  += __shfl_down(local,  off, 64);
        mlocal += __shfl_down(mlocal, off, 64);
    }
    __shared__ float s1[4], s2[4];
    int lane = threadIdx.x & 63, wid = threadIdx.x >> 6;
    if (lane == 0) { s1[wid] = local; s2[wid] = mlocal; }
    __syncthreads();
    if (threadIdx.x == 0) {
        pl[bid] = (double)(s1[0] + s1[1] + s1[2] + s1[3]);
        pm[bid] = (double)(s2[0] + s2[1] + s2[2] + s2[3]);
    }
}

__global__ void __launch_bounds__(256) finalize_kernel(
    const double* __restrict__ pl, const double* __restrict__ pm,
    float* __restrict__ out)
{
    double l = 0.0, m = 0.0;
    for (int idx = threadIdx.x; idx < NBLK_TOTAL; idx += 256) {
        double w = (idx < B1_END) ? 1.0 : (idx < B2_END) ? 4.0
                 : (idx < B4_END) ? 16.0 : (idx < B8_END) ? 64.0 : 256.0;
        l += w * pl[idx];
    }
    for (int idx = threadIdx.x; idx < B1_END; idx += 256) m += pm[idx];
    #pragma unroll
    for (int off = 32; off > 0; off >>= 1) {
        l += __shfl_down(l, off, 64);
        m += __shfl_down(m, off, 64);
    }
    __shared__ double sl[4], sm[4];
    int lane = threadIdx.x & 63, wid = threadIdx.x >> 6;
    if (lane == 0) { sl[wid] = l; sm[wid] = m; }
    __syncthreads();
    if (threadIdx.x == 0)
        out[0] = (float)((sl[0] + sl[1] + sl[2] + sl[3]) / (sm[0] + sm[1] + sm[2] + sm[3]));
}

extern "C" void kernel_launch(void* const* d_in, const int* in_sizes, int n_in,
                              void* d_out, int out_size, void* d_ws, size_t ws_size,
                              hipStream_t stream) {
    (void)in_sizes; (void)n_in; (void)out_size; (void)ws_size;
    const float* imgs = (const float*)d_in[0];
    const float* mask = (const float*)d_in[1];
    const float* pred[5];
    const float* pw[5];
    const float* pb[5];
    for (int k = 0; k < 5; ++k) {
        pred[k] = (const float*)d_in[2 + 3 * k];
        pw[k]   = (const float*)d_in[3 + 3 * k];
        pb[k]   = (const float*)d_in[4 + 3 * k];
    }
    double* pl = (double*)d_ws;
    double* pm = pl + NBLK_TOTAL;

    fused_kernel<<<NBLK_TOTAL, 256, 0, stream>>>(
        imgs, mask,
        pred[0], pred[1], pred[2], pred[3], pred[4],
        pw[0], pw[1], pw[2], pw[3], pw[4],
        pb[0], pb[1], pb[2], pb[3], pb[4],
        pl, pm);
    finalize_kernel<<<1, 256, 0, stream>>>(pl, pm, (float*)d_out);
}

// Round 7
// 71.692 us; speedup vs baseline: 1.1088x; 1.1088x over previous
//
#include <hip/hip_runtime.h>

#define N_IMG 32
#define H_IMG 224
#define W_IMG 224

// Fused grid, one OUTPUT PER THREAD, heavy scales first:
// S=16: [0, 25)        32*14*14   (last block partial)
// S=8 : [25, 123)      32*28*28
// S=4 : [123, 515)     32*56*56
// S=2 : [515, 2083)    32*112*112
// S=1 : [2083, 8355)   32*224*224
#define BS16_END 25
#define BS8_END 123
#define BS4_END 515
#define BS2_END 2083
#define NBLK_TOTAL 8355

__device__ __forceinline__ int reflect_idx(int i, int n) {
    if (i < 0) return -i;
    if (i >= n) return 2 * n - 2 - i;
    return i;
}

// bin = floor(atan2(gx,gy)/pi*9) mod 9 without atan2: direction-only sector count.
__device__ __forceinline__ int bin_from_g(float gx, float gy) {
    float u = gx * __builtin_copysignf(1.0f, gy);
    float w = __builtin_fabsf(gy);
    const float T[9] = {-5.6712818f, -1.7320508f, -0.83909963f, -0.36397023f,
                        0.0f, 0.36397023f, 0.83909963f, 1.7320508f, 5.6712818f};
    int c = 0;
    #pragma unroll
    for (int k = 0; k < 9; ++k) c += (u >= T[k] * w) ? 1 : 0;
    int b = c + 4;
    return (b >= 9) ? b - 9 : b;
}

template <int S>
__device__ __forceinline__ void scale_body(int rel_bid,
    const float* __restrict__ imgs, const float* __restrict__ mask,
    const float* __restrict__ pred,
    const float* spwT, const float* spb, const float* sA, const float* sB,
    float Cc, float& local, float& mlocal)
{
    constexpr int Hs = H_IMG / S, Ws = W_IMG / S;
    int vt = rel_bid * 256 + (int)threadIdx.x;
    if (vt >= N_IMG * Hs * Ws) return;
    int j = vt % Ws;
    int t = vt / Ws;
    int i = t % Hs;
    int n = t / Hs;

    // ---- mask pooling: fully unrolled, independent loads ----
    float M;
    const float* mbase = mask + (size_t)n * H_IMG * W_IMG + (size_t)(i * S) * W_IMG + j * S;
    if constexpr (S == 1) {
        M = mbase[0];
    } else if constexpr (S == 2) {
        float2 a = *(const float2*)(mbase);
        float2 b = *(const float2*)(mbase + W_IMG);
        M = (a.x + a.y + b.x + b.y) * 0.25f;
    } else {
        float msum = 0.0f;
        #pragma unroll
        for (int a = 0; a < S; ++a) {
            const float* mr = mbase + (size_t)a * W_IMG;
            #pragma unroll
            for (int q = 0; q < S / 4; ++q) {
                float4 fv = *(const float4*)(mr + q * 4);
                msum += (fv.x + fv.y) + (fv.z + fv.w);
            }
        }
        M = msum * (1.0f / (float)(S * S));
    }

    int y = i * S, x = j * S;
    int y0 = reflect_idx(y - 1, H_IMG), y2 = reflect_idx(y + 1, H_IMG);
    int x0 = reflect_idx(x - 1, W_IMG), x2 = reflect_idx(x + 1, W_IMG);
    constexpr size_t cstride = (size_t)Hs * Ws;

    float d2 = 0.0f;
    #pragma unroll
    for (int c = 0; c < 3; ++c) {
        const float* im = imgs + (size_t)(n * 3 + c) * H_IMG * W_IMG;
        const float* q0 = im + (size_t)y0 * W_IMG;
        const float* q1 = im + (size_t)y  * W_IMG;
        const float* q2 = im + (size_t)y2 * W_IMG;
        // 8 img loads (center unused)
        float p00 = q0[x0], p01 = q0[x], p02 = q0[x2];
        float p10 = q1[x0],             p12 = q1[x2];
        float p20 = q2[x0], p21 = q2[x], p22 = q2[x2];

        // stage 9 preds (independent, fly under the sobel math)
        const float* pr = pred + ((size_t)(n * 27 + c * 9) * Hs + i) * Ws + j;
        float p[9];
        #pragma unroll
        for (int o = 0; o < 9; ++o) p[o] = pr[o * cstride];

        float gx = (p00 - p02) + 2.0f * (p10 - p12) + (p20 - p22);
        float gy = (p00 - p20) + 2.0f * (p01 - p21) + (p02 - p22);
        float mag = sqrtf(gx * gx + gy * gy);
        int bn = bin_from_g(gx, gy);
        float nrm2 = fmaf(mag, fmaf(mag, sA[bn], 2.0f * sB[bn]), Cc);
        float inv = 1.0f / fmaxf(sqrtf(nrm2), 1e-12f);

        #pragma unroll
        for (int o = 0; o < 9; ++o) {
            float h = fmaf(spwT[bn * 9 + o], mag, spb[o]) * inv;
            float dd = p[o] - h;
            d2 += dd * dd;
        }
    }

    local = M * d2 * (1.0f / 27.0f);
    if constexpr (S == 1) mlocal = M;   // sum over s=1 outputs == sum(mask)
}

__global__ void __launch_bounds__(256) fused_kernel(
    const float* __restrict__ imgs, const float* __restrict__ mask,
    const float* __restrict__ pred0, const float* __restrict__ pred1,
    const float* __restrict__ pred2, const float* __restrict__ pred3,
    const float* __restrict__ pred4,
    const float* __restrict__ pw0, const float* __restrict__ pw1,
    const float* __restrict__ pw2, const float* __restrict__ pw3,
    const float* __restrict__ pw4,
    const float* __restrict__ pb0, const float* __restrict__ pb1,
    const float* __restrict__ pb2, const float* __restrict__ pb3,
    const float* __restrict__ pb4,
    double* __restrict__ pl, double* __restrict__ pm)
{
    __shared__ float spwT[81];   // spwT[b*9+o] = pw[o*9+b]
    __shared__ float spb[9];
    __shared__ float sA[9], sB[9], sC[1];

    int bid = blockIdx.x;
    // heavy scales first: [0,25)=s16(k0), [25,123)=s8(k1), [123,515)=s4(k2),
    // [515,2083)=s2(k3), [2083,...)=s1(k4)
    const float* pw;  const float* pb;
    if (bid < BS16_END)      { pw = pw0; pb = pb0; }
    else if (bid < BS8_END)  { pw = pw1; pb = pb1; }
    else if (bid < BS4_END)  { pw = pw2; pb = pb2; }
    else if (bid < BS2_END)  { pw = pw3; pb = pb3; }
    else                     { pw = pw4; pb = pb4; }

    if (threadIdx.x < 81) {
        int o = threadIdx.x / 9, b = threadIdx.x % 9;
        spwT[b * 9 + o] = pw[threadIdx.x];
    }
    if (threadIdx.x < 9) spb[threadIdx.x] = pb[threadIdx.x];
    __syncthreads();
    if (threadIdx.x < 9) {
        float A = 0.0f, B = 0.0f;
        #pragma unroll
        for (int o = 0; o < 9; ++o) {
            float w = spwT[threadIdx.x * 9 + o];
            A += w * w;
            B += w * spb[o];
        }
        sA[threadIdx.x] = A;
        sB[threadIdx.x] = B;
        if (threadIdx.x == 0) {
            float Cc = 0.0f;
            #pragma unroll
            for (int o = 0; o < 9; ++o) Cc += spb[o] * spb[o];
            sC[0] = Cc;
        }
    }
    __syncthreads();
    float Cc = sC[0];

    float local = 0.0f, mlocal = 0.0f;
    if (bid < BS16_END)      scale_body<16>(bid,            imgs, mask, pred0, spwT, spb, sA, sB, Cc, local, mlocal);
    else if (bid < BS8_END)  scale_body<8>(bid - BS16_END,  imgs, mask, pred1, spwT, spb, sA, sB, Cc, local, mlocal);
    else if (bid < BS4_END)  scale_body<4>(bid - BS8_END,   imgs, mask, pred2, spwT, spb, sA, sB, Cc, local, mlocal);
    else if (bid < BS2_END)  scale_body<2>(bid - BS4_END,   imgs, mask, pred3, spwT, spb, sA, sB, Cc, local, mlocal);
    else                     scale_body<1>(bid - BS2_END,   imgs, mask, pred4, spwT, spb, sA, sB, Cc, local, mlocal);

    #pragma unroll
    for (int off = 32; off > 0; off >>= 1) {
        local  += __shfl_down(local,  off, 64);
        mlocal += __shfl_down(mlocal, off, 64);
    }
    __shared__ float s1[4], s2[4];
    int lane = threadIdx.x & 63, wid = threadIdx.x >> 6;
    if (lane == 0) { s1[wid] = local; s2[wid] = mlocal; }
    __syncthreads();
    if (threadIdx.x == 0) {
        pl[bid] = (double)(s1[0] + s1[1] + s1[2] + s1[3]);
        pm[bid] = (double)(s2[0] + s2[1] + s2[2] + s2[3]);
    }
}

__global__ void __launch_bounds__(256) finalize_kernel(
    const double* __restrict__ pl, const double* __restrict__ pm,
    float* __restrict__ out)
{
    double l = 0.0, m = 0.0;
    for (int idx = threadIdx.x; idx < NBLK_TOTAL; idx += 256) {
        double w = (idx < BS16_END) ? 256.0 : (idx < BS8_END) ? 64.0
                 : (idx < BS4_END) ? 16.0 : (idx < BS2_END) ? 4.0 : 1.0;
        l += w * pl[idx];
        m += pm[idx];   // pm is zero except s=1 blocks
    }
    #pragma unroll
    for (int off = 32; off > 0; off >>= 1) {
        l += __shfl_down(l, off, 64);
        m += __shfl_down(m, off, 64);
    }
    __shared__ double sl[4], sm[4];
    int lane = threadIdx.x & 63, wid = threadIdx.x >> 6;
    if (lane == 0) { sl[wid] = l; sm[wid] = m; }
    __syncthreads();
    if (threadIdx.x == 0)
        out[0] = (float)((sl[0] + sl[1] + sl[2] + sl[3]) / (sm[0] + sm[1] + sm[2] + sm[3]));
}

extern "C" void kernel_launch(void* const* d_in, const int* in_sizes, int n_in,
                              void* d_out, int out_size, void* d_ws, size_t ws_size,
                              hipStream_t stream) {
    (void)in_sizes; (void)n_in; (void)out_size; (void)ws_size;
    const float* imgs = (const float*)d_in[0];
    const float* mask = (const float*)d_in[1];
    const float* pred[5];
    const float* pw[5];
    const float* pb[5];
    for (int k = 0; k < 5; ++k) {
        pred[k] = (const float*)d_in[2 + 3 * k];
        pw[k]   = (const float*)d_in[3 + 3 * k];
        pb[k]   = (const float*)d_in[4 + 3 * k];
    }
    double* pl = (double*)d_ws;
    double* pm = pl + NBLK_TOTAL;

    fused_kernel<<<NBLK_TOTAL, 256, 0, stream>>>(
        imgs, mask,
        pred[0], pred[1], pred[2], pred[3], pred[4],
        pw[0], pw[1], pw[2], pw[3], pw[4],
        pb[0], pb[1], pb[2], pb[3], pb[4],
        pl, pm);
    finalize_kernel<<<1, 256, 0, stream>>>(pl, pm, (float*)d_out);
}

// Round 8
// 66.080 us; speedup vs baseline: 1.2030x; 1.0849x over previous
//
#include <hip/hip_runtime.h>

#define N_IMG 32
#define H_IMG 224
#define W_IMG 224

// Fused grid, heavy scales first:
// S=16: [0, 25)        32*14*14 threads  (last block partial)
// S=8 : [25, 123)      32*28*28
// S=4 : [123, 515)     32*56*56
// S=2 : [515, 2083)    32*112*112
// S=1 : [2083, 5219)   32*224*112 vec2-threads (2 outputs each)
#define BS16_END 25
#define BS8_END 123
#define BS4_END 515
#define BS2_END 2083
#define NBLK_TOTAL 5219

__device__ __forceinline__ int reflect_idx(int i, int n) {
    if (i < 0) return -i;
    if (i >= n) return 2 * n - 2 - i;
    return i;
}

// bin = floor(atan2(gx,gy)/pi*9) mod 9 without atan2: direction-only sector count.
__device__ __forceinline__ int bin_from_g(float gx, float gy) {
    float u = gx * __builtin_copysignf(1.0f, gy);
    float w = __builtin_fabsf(gy);
    const float T[9] = {-5.6712818f, -1.7320508f, -0.83909963f, -0.36397023f,
                        0.0f, 0.36397023f, 0.83909963f, 1.7320508f, 5.6712818f};
    int c = 0;
    #pragma unroll
    for (int k = 0; k < 9; ++k) c += (u >= T[k] * w) ? 1 : 0;
    int b = c + 4;
    return (b >= 9) ? b - 9 : b;
}

// ---------------- s=1, two outputs per thread ----------------
__device__ __forceinline__ void s1_body2(int rel_bid,
    const float* __restrict__ imgs, const float* __restrict__ mask,
    const float* __restrict__ pred,
    const float* spwT, const float* spb, const float* sA, const float* sB,
    float Cc, float& local, float& mlocal)
{
    constexpr int WsV = W_IMG / 2;
    int vt = rel_bid * 256 + (int)threadIdx.x;
    int jv = vt % WsV;
    int t  = vt / WsV;
    int i  = t % H_IMG;
    int n  = t / H_IMG;
    int j0 = jv * 2;

    constexpr size_t cstride = (size_t)H_IMG * W_IMG;
    float2 mv = *(const float2*)(mask + (size_t)n * cstride + (size_t)i * W_IMG + j0);

    int y0 = reflect_idx(i - 1, H_IMG), y2 = reflect_idx(i + 1, H_IMG);
    int xl = reflect_idx(j0 - 1, W_IMG);
    int xr = reflect_idx(j0 + 2, W_IMG);

    float d2[2] = {0.0f, 0.0f};
    #pragma unroll
    for (int c = 0; c < 3; ++c) {
        const float* im = imgs + (size_t)(n * 3 + c) * cstride;
        const float* q0 = im + (size_t)y0 * W_IMG;
        const float* q1 = im + (size_t)i  * W_IMG;
        const float* q2 = im + (size_t)y2 * W_IMG;

        // img loads first (oldest in queue -> sobel waits only on these)
        float r0[4], r1[4], r2[4];
        float2 f;
        r0[0] = q0[xl]; f = *(const float2*)(q0 + j0); r0[1] = f.x; r0[2] = f.y; r0[3] = q0[xr];
        r1[0] = q1[xl]; f = *(const float2*)(q1 + j0); r1[1] = f.x; r1[2] = f.y; r1[3] = q1[xr];
        r2[0] = q2[xl]; f = *(const float2*)(q2 + j0); r2[1] = f.x; r2[2] = f.y; r2[3] = q2[xr];

        // stage 9 float2 preds (fly under the sobel math)
        const float* pr = pred + ((size_t)(n * 27 + c * 9) * H_IMG + i) * W_IMG + j0;
        float2 p[9];
        #pragma unroll
        for (int o = 0; o < 9; ++o) p[o] = *(const float2*)(pr + o * cstride);

        #pragma unroll
        for (int v = 0; v < 2; ++v) {
            float gx = (r0[v] - r0[v + 2]) + 2.0f * (r1[v] - r1[v + 2]) + (r2[v] - r2[v + 2]);
            float gy = (r0[v] - r2[v]) + 2.0f * (r0[v + 1] - r2[v + 1]) + (r0[v + 2] - r2[v + 2]);
            float mag = sqrtf(gx * gx + gy * gy);
            int bn = bin_from_g(gx, gy);
            float nrm2 = fmaf(mag, fmaf(mag, sA[bn], 2.0f * sB[bn]), Cc);
            float inv = 1.0f / fmaxf(sqrtf(nrm2), 1e-12f);
            #pragma unroll
            for (int o = 0; o < 9; ++o) {
                float h = fmaf(spwT[bn * 9 + o], mag, spb[o]) * inv;
                float pv = (v == 0) ? p[o].x : p[o].y;
                float dd = pv - h;
                d2[v] += dd * dd;
            }
        }
    }

    local  = (mv.x * d2[0] + mv.y * d2[1]) * (1.0f / 27.0f);
    mlocal = mv.x + mv.y;   // sum over s=1 == sum(mask)
}

// ---------------- generic S>=2, one output per thread ----------------
template <int S>
__device__ __forceinline__ void scale_body(int rel_bid,
    const float* __restrict__ imgs, const float* __restrict__ mask,
    const float* __restrict__ pred,
    const float* spwT, const float* spb, const float* sA, const float* sB,
    float Cc, float& local)
{
    constexpr int Hs = H_IMG / S, Ws = W_IMG / S;
    int vt = rel_bid * 256 + (int)threadIdx.x;
    if (vt >= N_IMG * Hs * Ws) return;
    int j = vt % Ws;
    int t = vt / Ws;
    int i = t % Hs;
    int n = t / Hs;

    // ---- mask pooling: fully unrolled, independent loads ----
    float M;
    const float* mbase = mask + (size_t)n * H_IMG * W_IMG + (size_t)(i * S) * W_IMG + j * S;
    if constexpr (S == 2) {
        float2 a = *(const float2*)(mbase);
        float2 b = *(const float2*)(mbase + W_IMG);
        M = (a.x + a.y + b.x + b.y) * 0.25f;
    } else {
        float msum = 0.0f;
        #pragma unroll
        for (int a = 0; a < S; ++a) {
            const float* mr = mbase + (size_t)a * W_IMG;
            #pragma unroll
            for (int q = 0; q < S / 4; ++q) {
                float4 fv = *(const float4*)(mr + q * 4);
                msum += (fv.x + fv.y) + (fv.z + fv.w);
            }
        }
        M = msum * (1.0f / (float)(S * S));
    }

    int y = i * S, x = j * S;
    int y0 = reflect_idx(y - 1, H_IMG), y2 = reflect_idx(y + 1, H_IMG);
    int x0 = reflect_idx(x - 1, W_IMG), x2 = reflect_idx(x + 1, W_IMG);
    constexpr size_t cstride = (size_t)Hs * Ws;

    float d2 = 0.0f;
    #pragma unroll
    for (int c = 0; c < 3; ++c) {
        const float* im = imgs + (size_t)(n * 3 + c) * H_IMG * W_IMG;
        const float* q0 = im + (size_t)y0 * W_IMG;
        const float* q1 = im + (size_t)y  * W_IMG;
        const float* q2 = im + (size_t)y2 * W_IMG;
        float p00 = q0[x0], p01 = q0[x], p02 = q0[x2];
        float p10 = q1[x0],             p12 = q1[x2];
        float p20 = q2[x0], p21 = q2[x], p22 = q2[x2];

        const float* pr = pred + ((size_t)(n * 27 + c * 9) * Hs + i) * Ws + j;
        float p[9];
        #pragma unroll
        for (int o = 0; o < 9; ++o) p[o] = pr[o * cstride];

        float gx = (p00 - p02) + 2.0f * (p10 - p12) + (p20 - p22);
        float gy = (p00 - p20) + 2.0f * (p01 - p21) + (p02 - p22);
        float mag = sqrtf(gx * gx + gy * gy);
        int bn = bin_from_g(gx, gy);
        float nrm2 = fmaf(mag, fmaf(mag, sA[bn], 2.0f * sB[bn]), Cc);
        float inv = 1.0f / fmaxf(sqrtf(nrm2), 1e-12f);

        #pragma unroll
        for (int o = 0; o < 9; ++o) {
            float h = fmaf(spwT[bn * 9 + o], mag, spb[o]) * inv;
            float dd = p[o] - h;
            d2 += dd * dd;
        }
    }

    local = M * d2 * (1.0f / 27.0f);
}

__global__ void __launch_bounds__(256) fused_kernel(
    const float* __restrict__ imgs, const float* __restrict__ mask,
    const float* __restrict__ pred0, const float* __restrict__ pred1,
    const float* __restrict__ pred2, const float* __restrict__ pred3,
    const float* __restrict__ pred4,
    const float* __restrict__ pw0, const float* __restrict__ pw1,
    const float* __restrict__ pw2, const float* __restrict__ pw3,
    const float* __restrict__ pw4,
    const float* __restrict__ pb0, const float* __restrict__ pb1,
    const float* __restrict__ pb2, const float* __restrict__ pb3,
    const float* __restrict__ pb4,
    double* __restrict__ pl, double* __restrict__ pm)
{
    __shared__ float spwT[81];   // spwT[b*9+o] = pw[o*9+b]
    __shared__ float spb[9];
    __shared__ float sA[9], sB[9], sC[1];

    int bid = blockIdx.x;
    const float* pw;  const float* pb;
    if (bid < BS16_END)      { pw = pw0; pb = pb0; }
    else if (bid < BS8_END)  { pw = pw1; pb = pb1; }
    else if (bid < BS4_END)  { pw = pw2; pb = pb2; }
    else if (bid < BS2_END)  { pw = pw3; pb = pb3; }
    else                     { pw = pw4; pb = pb4; }

    if (threadIdx.x < 81) {
        int o = threadIdx.x / 9, b = threadIdx.x % 9;
        spwT[b * 9 + o] = pw[threadIdx.x];
    }
    if (threadIdx.x < 9) spb[threadIdx.x] = pb[threadIdx.x];
    __syncthreads();
    if (threadIdx.x < 9) {
        float A = 0.0f, B = 0.0f;
        #pragma unroll
        for (int o = 0; o < 9; ++o) {
            float w = spwT[threadIdx.x * 9 + o];
            A += w * w;
            B += w * spb[o];
        }
        sA[threadIdx.x] = A;
        sB[threadIdx.x] = B;
        if (threadIdx.x == 0) {
            float Cc = 0.0f;
            #pragma unroll
            for (int o = 0; o < 9; ++o) Cc += spb[o] * spb[o];
            sC[0] = Cc;
        }
    }
    __syncthreads();
    float Cc = sC[0];

    float local = 0.0f, mlocal = 0.0f;
    if (bid < BS16_END)      scale_body<16>(bid,            imgs, mask, pred0, spwT, spb, sA, sB, Cc, local);
    else if (bid < BS8_END)  scale_body<8>(bid - BS16_END,  imgs, mask, pred1, spwT, spb, sA, sB, Cc, local);
    else if (bid < BS4_END)  scale_body<4>(bid - BS8_END,   imgs, mask, pred2, spwT, spb, sA, sB, Cc, local);
    else if (bid < BS2_END)  scale_body<2>(bid - BS4_END,   imgs, mask, pred3, spwT, spb, sA, sB, Cc, local);
    else                     s1_body2(bid - BS2_END,        imgs, mask, pred4, spwT, spb, sA, sB, Cc, local, mlocal);

    #pragma unroll
    for (int off = 32; off > 0; off >>= 1) {
        local  += __shfl_down(local,  off, 64);
        mlocal += __shfl_down(mlocal, off, 64);
    }
    __shared__ float s1[4], s2[4];
    int lane = threadIdx.x & 63, wid = threadIdx.x >> 6;
    if (lane == 0) { s1[wid] = local; s2[wid] = mlocal; }
    __syncthreads();
    if (threadIdx.x == 0) {
        pl[bid] = (double)(s1[0] + s1[1] + s1[2] + s1[3]);
        pm[bid] = (double)(s2[0] + s2[1] + s2[2] + s2[3]);
    }
}

__global__ void __launch_bounds__(256) finalize_kernel(
    const double* __restrict__ pl, const double* __restrict__ pm,
    float* __restrict__ out)
{
    double l = 0.0, m = 0.0;
    for (int idx = threadIdx.x; idx < NBLK_TOTAL; idx += 256) {
        double w = (idx < BS16_END) ? 256.0 : (idx < BS8_END) ? 64.0
                 : (idx < BS4_END) ? 16.0 : (idx < BS2_END) ? 4.0 : 1.0;
        l += w * pl[idx];
        m += pm[idx];   // nonzero only for s=1 blocks
    }
    #pragma unroll
    for (int off = 32; off > 0; off >>= 1) {
        l += __shfl_down(l, off, 64);
        m += __shfl_down(m, off, 64);
    }
    __shared__ double sl[4], sm[4];
    int lane = threadIdx.x & 63, wid = threadIdx.x >> 6;
    if (lane == 0) { sl[wid] = l; sm[wid] = m; }
    __syncthreads();
    if (threadIdx.x == 0)
        out[0] = (float)((sl[0] + sl[1] + sl[2] + sl[3]) / (sm[0] + sm[1] + sm[2] + sm[3]));
}

extern "C" void kernel_launch(void* const* d_in, const int* in_sizes, int n_in,
                              void* d_out, int out_size, void* d_ws, size_t ws_size,
                              hipStream_t stream) {
    (void)in_sizes; (void)n_in; (void)out_size; (void)ws_size;
    const float* imgs = (const float*)d_in[0];
    const float* mask = (const float*)d_in[1];
    const float* pred[5];
    const float* pw[5];
    const float* pb[5];
    for (int k = 0; k < 5; ++k) {
        pred[k] = (const float*)d_in[2 + 3 * k];
        pw[k]   = (const float*)d_in[3 + 3 * k];
        pb[k]   = (const float*)d_in[4 + 3 * k];
    }
    double* pl = (double*)d_ws;
    double* pm = pl + NBLK_TOTAL;

    fused_kernel<<<NBLK_TOTAL, 256, 0, stream>>>(
        imgs, mask,
        pred[0], pred[1], pred[2], pred[3], pred[4],
        pw[0], pw[1], pw[2], pw[3], pw[4],
        pb[0], pb[1], pb[2], pb[3], pb[4],
        pl, pm);
    finalize_kernel<<<1, 256, 0, stream>>>(pl, pm, (float*)d_out);
}